// Round 7
// baseline (228214.087 us; speedup 1.0000x reference)
//
#include <hip/hip_runtime.h>
#include <hip/hip_bf16.h>

// 8 independent LSTMs (HID=512, input=1 scalar/step) x T=256, batch 128, then a
// tiny (B,T)->(B,8) projection.
//
// Round 7: XCD-local h exchange with provably-terminating control.
//  Liveness facts used: (r3-proven) all 32 blocks of a branch are co-resident
//  and progress. Everything needing MORE than that is BOUNDED (timeout =>
//  fall back to the r3 MALL protocol, 3.88ms, known-correct).
//   - entry: every block publishes 0xA5|XCC_ID to vx[blockIdx] (sc0 sc1).
//   - leader (jt==0, wave 0) bounded-polls all 256 tags; verdict: my branch
//     uniform on XCD x AND no other block on x AND x<8. Publishes verdict to
//     vdict[n]; followers wait on own leader only.
//   - pure mode: h + flags live in XCD-INDEXED regions (region[x] only ever
//     touched by XCD x, launch after launch -> stale dirty L2 lines are always
//     overwritten in the same L2 by the scrub; no cross-XCD aliasing).
//     h stores/loads sc0 (L2-local). Flags: owner-scrubbed, double-stored
//     (sc0 + sc0 sc1); poll sc0 with escalation to sc0 sc1 => termination does
//     not depend on any cache-model assumption.
//   - impure mode: exact r3 protocol on branch-indexed buffers.

#define NBR   8
#define BATCH 128
#define HIDN  512
#define TLEN  256

typedef __attribute__((ext_vector_type(8))) short bf16x8;
typedef __attribute__((ext_vector_type(4))) float f32x4;

__device__ __forceinline__ unsigned short bf16_rne(float f) {
  unsigned int u = __float_as_uint(f);
  u += 0x7FFFu + ((u >> 16) & 1u);
  return (unsigned short)(u >> 16);
}

__device__ __forceinline__ float sigm(float x) {
  return __builtin_amdgcn_rcpf(1.0f + __expf(-x));
}
__device__ __forceinline__ float tanh_(float x) {
  float ax = fabsf(x);
  float e  = __expf(-2.0f * ax);
  float t  = (1.0f - e) * __builtin_amdgcn_rcpf(1.0f + e);
  return copysignf(t, x);
}

#define HLOADX(d, p, OFF, SC) \
  asm volatile("global_load_dwordx4 %0, %1, off offset:" OFF " " SC \
               : "=v"(d) : "v"(p))
#define DLOADX(d, p, SC) \
  asm volatile("global_load_dword %0, %1, off " SC : "=v"(d) : "v"(p))
#define QSTOREX(p, v, SC) \
  asm volatile("global_store_dwordx2 %0, %1, off " SC \
               :: "v"(p), "v"(v) : "memory")
#define QSTOREXO(p, v, OFF, SC) \
  asm volatile("global_store_dwordx2 %0, %1, off offset:" OFF " " SC \
               :: "v"(p), "v"(v) : "memory")
#define DSTOREX(p, v, SC) \
  asm volatile("global_store_dword %0, %1, off " SC \
               :: "v"(p), "v"(v) : "memory")
#define WAITV(N) asm volatile("s_waitcnt vmcnt(" #N ")" ::: "memory")

#define CHUNK_LOAD(BUF, P0, P1, SC) do {      \
    HLOADX((BUF)[0], (P0), "0",   SC);        \
    HLOADX((BUF)[1], (P1), "0",   SC);        \
    HLOADX((BUF)[2], (P0), "64",  SC);        \
    HLOADX((BUF)[3], (P1), "64",  SC);        \
    HLOADX((BUF)[4], (P0), "128", SC);        \
    HLOADX((BUF)[5], (P1), "128", SC);        \
    HLOADX((BUF)[6], (P0), "192", SC);        \
    HLOADX((BUF)[7], (P1), "192", SC);        \
  } while (0)

#define MFMA_CHUNK(C) do {                                                    \
    _Pragma("unroll")                                                         \
    for (int k4 = 0; k4 < 4; ++k4) {                                          \
      const int ks = 4 * (C) + k4;                                            \
      bf16x8 wf[4];                                                           \
      _Pragma("unroll")                                                       \
      for (int tp = 0; tp < 4; ++tp)                                          \
        wf[tp] = __builtin_bit_cast(bf16x8, Wlds[wrow[tp] + ((4 * ks + q) ^ swz)]); \
      _Pragma("unroll")                                                       \
      for (int tp = 0; tp < 4; ++tp) {                                        \
        acc[tp][0] = __builtin_amdgcn_mfma_f32_16x16x32_bf16(                 \
            wf[tp], __builtin_bit_cast(bf16x8, hvv[C][2 * k4 + 0]), acc[tp][0], 0, 0, 0); \
        acc[tp][1] = __builtin_amdgcn_mfma_f32_16x16x32_bf16(                 \
            wf[tp], __builtin_bit_cast(bf16x8, hvv[C][2 * k4 + 1]), acc[tp][1], 0, 0, 0); \
      }                                                                       \
    }                                                                         \
  } while (0)

// FM==1: pure (sc0 h-exchange, double-store flags, escalating poll).
// FM==0: exact r3 MALL protocol.
#define STEP_LOOP(SC, FM)                                                     \
  for (int t = 0; t < TLEN; ++t) {                                            \
    f32x4 acc[4][2];                                                          \
    _Pragma("unroll")                                                         \
    for (int tp = 0; tp < 4; ++tp)                                            \
      { acc[tp][0] = (f32x4){0.f,0.f,0.f,0.f}; acc[tp][1] = (f32x4){0.f,0.f,0.f,0.f}; } \
    const char* pc0 = curB + hoff0;                                           \
    const char* pc1 = curB + hoff1;                                           \
    uint4 hvv[4][8];                                                          \
    CHUNK_LOAD(hvv[0], pc0,       pc1,       SC);                             \
    CHUNK_LOAD(hvv[1], pc0 + 256, pc1 + 256, SC);                             \
    CHUNK_LOAD(hvv[2], pc0 + 512, pc1 + 512, SC);                             \
    CHUNK_LOAD(hvv[3], pc0 + 768, pc1 + 768, SC);                             \
    WAITV(24); MFMA_CHUNK(0);                                                 \
    WAITV(16); MFMA_CHUNK(1);                                                 \
    WAITV(8);  MFMA_CHUNK(2);                                                 \
    WAITV(0);  MFMA_CHUNK(3);                                                 \
    const float cv[2] = { c_in[bb0 * 256 + t], c_in[bb1 * 256 + t] };         \
    _Pragma("unroll")                                                         \
    for (int nt = 0; nt < 2; ++nt) {                                          \
      unsigned int lo = 0, hi = 0;                                            \
      float hv3 = 0.f;                                                        \
      _Pragma("unroll")                                                       \
      for (int r = 0; r < 4; ++r) {                                           \
        float gi = acc[0][nt][r] + wih_g[0][r] * cv[nt] + bias_g[0][r];       \
        float gf = acc[1][nt][r] + wih_g[1][r] * cv[nt] + bias_g[1][r];       \
        float gg = acc[2][nt][r] + wih_g[2][r] * cv[nt] + bias_g[2][r];       \
        float go = acc[3][nt][r] + wih_g[3][r] * cv[nt] + bias_g[3][r];       \
        float ncc = sigm(gf) * cc[nt][r] + sigm(gi) * tanh_(gg);              \
        cc[nt][r] = ncc;                                                      \
        float hval = sigm(go) * tanh_(ncc);                                   \
        unsigned int hb16 = bf16_rne(hval);                                   \
        if (r == 0) lo = hb16;                                                \
        if (r == 1) lo |= hb16 << 16;                                         \
        if (r == 2) hi = hb16;                                                \
        if (r == 3) { hi |= hb16 << 16; hv3 = hval; }                         \
      }                                                                       \
      unsigned long long pack = (unsigned long long)lo | ((unsigned long long)hi << 32); \
      QSTOREX(nxtB + (nt ? soff1 : soff0), pack, SC);                         \
      if (jt == 31 && q == 3)                                                 \
        ys[t * (NBR * BATCH) + n * BATCH + (nt ? bb1 : bb0)] = hv3;           \
    }                                                                         \
    if (t == TLEN - 1) break;                                                 \
    WAITV(0);                                                                 \
    const unsigned tgt = (unsigned)(t + 1);                                   \
    if (FM) {                                                                 \
      if (lane == 0) { DSTOREX(myflag, tgt, "sc0");                           \
                       DSTOREX(myflag, tgt, "sc0 sc1"); }                     \
      int spins = 0;                                                          \
      for (;;) {                                                              \
        unsigned f0v, f1v;                                                    \
        if (spins < 8192) { DLOADX(f0v, pf0, "sc0"); DLOADX(f1v, pf1, "sc0"); } \
        else { DLOADX(f0v, pf0, "sc0 sc1"); DLOADX(f1v, pf1, "sc0 sc1"); }    \
        WAITV(0);                                                             \
        if (__all((int)(f0v >= tgt && f1v >= tgt))) break;                    \
        ++spins; __builtin_amdgcn_s_sleep(1);                                 \
      }                                                                       \
    } else {                                                                  \
      if (lane == 0) DSTOREX(myflag, tgt, "sc0 sc1");                         \
      for (;;) {                                                              \
        unsigned f0v, f1v;                                                    \
        DLOADX(f0v, pf0, "sc0 sc1");                                          \
        DLOADX(f1v, pf1, "sc0 sc1");                                          \
        WAITV(0);                                                             \
        if (__all((int)(f0v >= tgt && f1v >= tgt))) break;                    \
        __builtin_amdgcn_s_sleep(1);                                          \
      }                                                                       \
    }                                                                         \
    char* tsw = curB; curB = nxtB; nxtB = tsw;                                \
  }

__global__ __launch_bounds__(256, 1) void lstm_main(
    const float* __restrict__ c_in,   // (128,256)
    const float* __restrict__ Wih,    // (8,2048)
    const float* __restrict__ Whh,    // (8,2048,512)
    const float* __restrict__ b_ih,   // (8,2048)
    const float* __restrict__ b_hh,   // (8,2048)
    char* __restrict__ hImp,          // 2MB: impure ping+pong (8,128,512)bf16 x2, pre-zeroed
    char* __restrict__ hPure,         // 2MB: 8 XCD regions x (128KB ping + 128KB pong)
    float* __restrict__ ys,           // (256,8,128)
    unsigned int* __restrict__ iflags,// 8x128 impure flags, pre-zeroed
    unsigned int* __restrict__ pflags,// 8x128 pure flags (XCD-indexed), owner-scrubbed
    unsigned int* __restrict__ vx,    // 256 tagged XCC slots, pre-zeroed
    unsigned int* __restrict__ vdict, // 8 verdicts, pre-zeroed
    unsigned int* __restrict__ ibar)  // 8x32 init-barrier slots (XCD-indexed), pre-zeroed
{
  __shared__ uint4 Wlds[4096];  // 64KB

  const int tid  = threadIdx.x;
  const int lane = tid & 63;
  const int w    = tid >> 6;
  const int ln15 = lane & 15;
  const int q    = lane >> 4;
  const int n    = blockIdx.x & 7;    // branch
  const int jt   = blockIdx.x >> 3;   // 0..31 hidden-col tile
  const int j0   = jt << 4;
  const int swz  = ln15 & 7;

  // ---- publish tagged XCC_ID (straight-line, at entry) ----
  unsigned xcc_raw;
  asm volatile("s_getreg_b32 %0, hwreg(HW_REG_XCC_ID)" : "=s"(xcc_raw));
  const unsigned xcc = xcc_raw & 0xFu;
  if (tid == 0) DSTOREX(&vx[blockIdx.x], 0xA5000000u | xcc, "sc0 sc1");

  // ---- stage Whh slice -> LDS bf16 (once) ----
  for (int idx = tid; idx < 4096; idx += 256) {
    int row  = idx >> 6;
    int kc   = idx & 63;
    int tp   = row >> 4;
    int wcol = row & 15;
    const float* src = Whh + ((size_t)(n * 2048 + tp * 512 + j0 + wcol) * 512 + kc * 8);
    float4 f0 = *(const float4*)(src);
    float4 f1 = *(const float4*)(src + 4);
    uint4 v;
    v.x = (unsigned)bf16_rne(f0.x) | ((unsigned)bf16_rne(f0.y) << 16);
    v.y = (unsigned)bf16_rne(f0.z) | ((unsigned)bf16_rne(f0.w) << 16);
    v.z = (unsigned)bf16_rne(f1.x) | ((unsigned)bf16_rne(f1.y) << 16);
    v.w = (unsigned)bf16_rne(f1.z) | ((unsigned)bf16_rne(f1.w) << 16);
    Wlds[(row << 6) | (kc ^ (wcol & 7))] = v;
  }

  float wih_g[4][4], bias_g[4][4];
#pragma unroll
  for (int tp = 0; tp < 4; ++tp)
#pragma unroll
    for (int r = 0; r < 4; ++r) {
      int g = n * 2048 + tp * 512 + j0 + 4 * q + r;
      wih_g[tp][r]  = Wih[g];
      bias_g[tp][r] = b_ih[g] + b_hh[g];
    }

  // ---- leader (jt==0, wave 0): bounded purity check, publish verdict ----
  if (jt == 0 && w == 0) {
    const unsigned ref = 0xA5000000u | xcc;
    unsigned v0 = 0, v1 = 0, v2 = 0, v3 = 0;
    int ok = 0;
    for (int it = 0; it < 16384; ++it) {
      DLOADX(v0, &vx[lane],       "sc0 sc1");
      DLOADX(v1, &vx[lane + 64],  "sc0 sc1");
      DLOADX(v2, &vx[lane + 128], "sc0 sc1");
      DLOADX(v3, &vx[lane + 192], "sc0 sc1");
      WAITV(0);
      if (__all((int)(((v0 & 0xFF000000u) == 0xA5000000u) &&
                      ((v1 & 0xFF000000u) == 0xA5000000u) &&
                      ((v2 & 0xFF000000u) == 0xA5000000u) &&
                      ((v3 & 0xFF000000u) == 0xA5000000u)))) { ok = 1; break; }
      __builtin_amdgcn_s_sleep(1);
    }
    unsigned verdict = 0;
    if (ok) {
      const bool mine = ((lane & 7) == n);   // slots with idx%8==n are my branch
      int uni = __all((int)(!mine || (v0 == ref && v1 == ref && v2 == ref && v3 == ref)));
      int oth = __all((int)( mine || (v0 != ref && v1 != ref && v2 != ref && v3 != ref)));
      verdict = (uni && oth && (xcc < 8u)) ? 1u : 0u;
    }
    if (lane == 0)
      DSTOREX(&vdict[n], 0xB5000000u | (verdict << 8) | xcc, "sc0 sc1");
  }

  // ---- all blocks: wait for own leader's verdict (r3-fact: leader runs) ----
  unsigned vd;
  for (;;) {
    DLOADX(vd, &vdict[n], "sc0 sc1");
    WAITV(0);
    if ((vd & 0xFF000000u) == 0xB5000000u) break;
    __builtin_amdgcn_s_sleep(2);
  }
  const int pure   = (int)((vd >> 8) & 1u);
  const unsigned x = vd & 0xFu;       // leader's XCD (== mine if pure)

  const int bb0 = w * 32 + ln15;
  const int bb1 = bb0 + 16;
  const size_t hoff0 = ((size_t)bb0 * 64 + q) * 16;   // batch-local byte offsets
  const size_t hoff1 = ((size_t)bb1 * 64 + q) * 16;
  const size_t soff0 = ((size_t)bb0 * 128 + jt * 4 + q) * 8;
  const size_t soff1 = ((size_t)bb1 * 128 + jt * 4 + q) * 8;

  const int wrow[4] = { (0 * 16 + ln15) << 6, (1 * 16 + ln15) << 6,
                        (2 * 16 + ln15) << 6, (3 * 16 + ln15) << 6 };

  float cc[2][4];
#pragma unroll
  for (int a = 0; a < 2; ++a)
#pragma unroll
    for (int r = 0; r < 4; ++r) cc[a][r] = 0.0f;

  char *curB, *nxtB;
  unsigned int *flagB;
  if (pure) { curB = hPure + (size_t)x * 262144; nxtB = curB + 131072; flagB = pflags + x * 128; }
  else      { curB = hImp  + (size_t)n * 131072; nxtB = curB + (size_t)NBR * 131072; flagB = iflags + n * 128; }
  unsigned int* myflag = flagB + jt * 4 + w;
  const unsigned int* pf0 = flagB + lane;
  const unsigned int* pf1 = flagB + 64 + lane;

  __syncthreads();   // Wlds ready; every wave has the verdict

  if (pure) {
    // scrub my 1/32 of region[x] (8KB) to 0 == initial h state; overwrite any
    // stale dirty lines (always in THIS XCD's L2 since regions are XCD-bound)
    char* rp = hPure + (size_t)x * 262144 + (size_t)jt * 8192;
    for (int i = tid; i < 1024; i += 256)
      QSTOREXO(rp + (size_t)i * 8, 0ull, "0", "sc0");
    // owner-scrub my 4 flag slots (double-store: L2 + MALL truth)
    if (tid < 4) {
      DSTOREX(&flagB[jt * 4 + tid], 0u, "sc0");
      DSTOREX(&flagB[jt * 4 + tid], 0u, "sc0 sc1");
    }
    WAITV(0);
    __syncthreads();
    // branch-local init barrier at MALL scope (terminates by r3-fact)
    if (tid == 0) DSTOREX(&ibar[x * 32 + jt], 1u, "sc0 sc1");
    for (;;) {
      unsigned iv;
      DLOADX(iv, &ibar[x * 32 + (lane & 31)], "sc0 sc1");
      WAITV(0);
      if (__all((int)(iv >= 1u))) break;
      __builtin_amdgcn_s_sleep(2);
    }
    STEP_LOOP("sc0", 1)
  } else {
    STEP_LOOP("sc0 sc1", 0)
  }
}

// out[b,j] = sum_t (sum_n ys[t,n,b] * x[n,b,t]) * Wl[j,t] + bl[j]
__global__ __launch_bounds__(256) void finalize_k(
    const float* __restrict__ ys, const float* __restrict__ x,
    const float* __restrict__ Wl, const float* __restrict__ bl,
    float* __restrict__ out)
{
  int b = blockIdx.x;
  int tid = threadIdx.x;  // = t
  __shared__ float r[256];
  float acc = 0.f;
#pragma unroll
  for (int n = 0; n < NBR; ++n)
    acc += ys[tid * (NBR * BATCH) + n * BATCH + b] * x[(n * BATCH + b) * 256 + tid];
  r[tid] = acc;
  __syncthreads();
  int wv = tid >> 6, ln = tid & 63;
#pragma unroll
  for (int jj = 0; jj < 2; ++jj) {
    int j = wv * 2 + jj;
    float p = 0.f;
#pragma unroll
    for (int t2 = ln; t2 < 256; t2 += 64) p += r[t2] * Wl[j * 256 + t2];
#pragma unroll
    for (int s = 32; s > 0; s >>= 1) p += __shfl_down(p, s, 64);
    if (ln == 0) out[b * NBR + j] = p + bl[j];
  }
}

extern "C" void kernel_launch(void* const* d_in, const int* in_sizes, int n_in,
                              void* d_out, int out_size, void* d_ws, size_t ws_size,
                              hipStream_t stream) {
  const float* x    = (const float*)d_in[0];
  const float* c    = (const float*)d_in[1];
  const float* Wih  = (const float*)d_in[2];
  const float* Whh  = (const float*)d_in[3];
  const float* b_ih = (const float*)d_in[4];
  const float* b_hh = (const float*)d_in[5];
  // d_in[6] = hn0 (zeros; impure ping buffer is memset, pure regions scrubbed in-kernel)
  const float* Wl   = (const float*)d_in[7];
  const float* bl   = (const float*)d_in[8];
  float* out = (float*)d_out;

  char* ws = (char*)d_ws;
  char*  hImp  = ws;                                   // 2MB (ping 1MB + pong 1MB)
  char*  hPure = ws + (2u << 20);                      // 2MB (8 x 256KB, XCD-indexed)
  float* ys    = (float*)(ws + (4u << 20));            // 1MB
  unsigned int* ctrl   = (unsigned int*)(ws + (5u << 20));
  unsigned int* iflags = ctrl;                         // 1024 u32
  unsigned int* pflags = ctrl + 1024;                  // 1024 u32
  unsigned int* vx     = ctrl + 2048;                  // 256 u32
  unsigned int* vdict  = ctrl + 2304;                  // 8 u32
  unsigned int* ibar   = ctrl + 2312;                  // 256 u32

  // ws re-poisoned (0xAA) before every timed launch: re-init every call.
  (void)hipMemsetAsync(hImp, 0, 1u << 20, stream);     // impure h(t=0) = 0
  (void)hipMemsetAsync(ctrl, 0, 2568u * sizeof(unsigned int), stream);

  lstm_main<<<256, 256, 0, stream>>>(c, Wih, Whh, b_ih, b_hh, hImp, hPure, ys,
                                     iflags, pflags, vx, vdict, ibar);
  finalize_k<<<BATCH, 256, 0, stream>>>(ys, x, Wl, bl, out);
}

// Round 8
// 6388.903 us; speedup vs baseline: 35.7204x; 35.7204x over previous
//
#include <hip/hip_runtime.h>
#include <hip/hip_bf16.h>

// 8 independent LSTMs (HID=512, input=1 scalar/step) x T=256, batch 128, then a
// tiny (B,T)->(B,8) projection.
//
// Round 8 = round 7 + per-CU L1 invalidation in the pure path.
//  r7 post-mortem: pure XCD-local mode ENGAGED (WRITE_SIZE 265->19MB) but every
//  step burned the full 8192-spin sc0 poll budget before the sc0sc1 fallback
//  saw the flag: sc0 loads can hit the per-CU L1, which gets no coherence
//  probes -> the hot polled line stays stale forever. Fix: `buffer_inv sc0`
//  (L1-only tag invalidate, the gfx940+ buffer_wbinvl1_vol) before each poll
//  load and once per step before the h loads. Escalation kept (threshold 128)
//  so a no-op buffer_inv degrades to ~4ms, never hangs. Impure path = r3.

#define NBR   8
#define BATCH 128
#define HIDN  512
#define TLEN  256

typedef __attribute__((ext_vector_type(8))) short bf16x8;
typedef __attribute__((ext_vector_type(4))) float f32x4;

__device__ __forceinline__ unsigned short bf16_rne(float f) {
  unsigned int u = __float_as_uint(f);
  u += 0x7FFFu + ((u >> 16) & 1u);
  return (unsigned short)(u >> 16);
}

__device__ __forceinline__ float sigm(float x) {
  return __builtin_amdgcn_rcpf(1.0f + __expf(-x));
}
__device__ __forceinline__ float tanh_(float x) {
  float ax = fabsf(x);
  float e  = __expf(-2.0f * ax);
  float t  = (1.0f - e) * __builtin_amdgcn_rcpf(1.0f + e);
  return copysignf(t, x);
}

#define HLOADX(d, p, OFF, SC) \
  asm volatile("global_load_dwordx4 %0, %1, off offset:" OFF " " SC \
               : "=v"(d) : "v"(p))
#define DLOADX(d, p, SC) \
  asm volatile("global_load_dword %0, %1, off " SC : "=v"(d) : "v"(p))
#define QSTOREX(p, v, SC) \
  asm volatile("global_store_dwordx2 %0, %1, off " SC \
               :: "v"(p), "v"(v) : "memory")
#define QSTOREXO(p, v, OFF, SC) \
  asm volatile("global_store_dwordx2 %0, %1, off offset:" OFF " " SC \
               :: "v"(p), "v"(v) : "memory")
#define DSTOREX(p, v, SC) \
  asm volatile("global_store_dword %0, %1, off " SC \
               :: "v"(p), "v"(v) : "memory")
#define WAITV(N) asm volatile("s_waitcnt vmcnt(" #N ")" ::: "memory")
// per-CU vector-L1 invalidate ONLY (sc0). NOT the r2 killer (that was sc1/L2).
#define INVL1() asm volatile("buffer_inv sc0" ::: "memory")

#define CHUNK_LOAD(BUF, P0, P1, SC) do {      \
    HLOADX((BUF)[0], (P0), "0",   SC);        \
    HLOADX((BUF)[1], (P1), "0",   SC);        \
    HLOADX((BUF)[2], (P0), "64",  SC);        \
    HLOADX((BUF)[3], (P1), "64",  SC);        \
    HLOADX((BUF)[4], (P0), "128", SC);        \
    HLOADX((BUF)[5], (P1), "128", SC);        \
    HLOADX((BUF)[6], (P0), "192", SC);        \
    HLOADX((BUF)[7], (P1), "192", SC);        \
  } while (0)

#define MFMA_CHUNK(C) do {                                                    \
    _Pragma("unroll")                                                         \
    for (int k4 = 0; k4 < 4; ++k4) {                                          \
      const int ks = 4 * (C) + k4;                                            \
      bf16x8 wf[4];                                                           \
      _Pragma("unroll")                                                       \
      for (int tp = 0; tp < 4; ++tp)                                          \
        wf[tp] = __builtin_bit_cast(bf16x8, Wlds[wrow[tp] + ((4 * ks + q) ^ swz)]); \
      _Pragma("unroll")                                                       \
      for (int tp = 0; tp < 4; ++tp) {                                        \
        acc[tp][0] = __builtin_amdgcn_mfma_f32_16x16x32_bf16(                 \
            wf[tp], __builtin_bit_cast(bf16x8, hvv[C][2 * k4 + 0]), acc[tp][0], 0, 0, 0); \
        acc[tp][1] = __builtin_amdgcn_mfma_f32_16x16x32_bf16(                 \
            wf[tp], __builtin_bit_cast(bf16x8, hvv[C][2 * k4 + 1]), acc[tp][1], 0, 0, 0); \
      }                                                                       \
    }                                                                         \
  } while (0)

// FM==1: pure (sc0 h-exchange, L1-inv poll, escalating fallback).
// FM==0: exact r3 MALL protocol.
#define STEP_LOOP(SC, FM)                                                     \
  for (int t = 0; t < TLEN; ++t) {                                            \
    f32x4 acc[4][2];                                                          \
    _Pragma("unroll")                                                         \
    for (int tp = 0; tp < 4; ++tp)                                            \
      { acc[tp][0] = (f32x4){0.f,0.f,0.f,0.f}; acc[tp][1] = (f32x4){0.f,0.f,0.f,0.f}; } \
    const char* pc0 = curB + hoff0;                                           \
    const char* pc1 = curB + hoff1;                                           \
    uint4 hvv[4][8];                                                          \
    CHUNK_LOAD(hvv[0], pc0,       pc1,       SC);                             \
    CHUNK_LOAD(hvv[1], pc0 + 256, pc1 + 256, SC);                             \
    CHUNK_LOAD(hvv[2], pc0 + 512, pc1 + 512, SC);                             \
    CHUNK_LOAD(hvv[3], pc0 + 768, pc1 + 768, SC);                             \
    WAITV(24); MFMA_CHUNK(0);                                                 \
    WAITV(16); MFMA_CHUNK(1);                                                 \
    WAITV(8);  MFMA_CHUNK(2);                                                 \
    WAITV(0);  MFMA_CHUNK(3);                                                 \
    const float cv[2] = { c_in[bb0 * 256 + t], c_in[bb1 * 256 + t] };         \
    _Pragma("unroll")                                                         \
    for (int nt = 0; nt < 2; ++nt) {                                          \
      unsigned int lo = 0, hi = 0;                                            \
      float hv3 = 0.f;                                                        \
      _Pragma("unroll")                                                       \
      for (int r = 0; r < 4; ++r) {                                           \
        float gi = acc[0][nt][r] + wih_g[0][r] * cv[nt] + bias_g[0][r];       \
        float gf = acc[1][nt][r] + wih_g[1][r] * cv[nt] + bias_g[1][r];       \
        float gg = acc[2][nt][r] + wih_g[2][r] * cv[nt] + bias_g[2][r];       \
        float go = acc[3][nt][r] + wih_g[3][r] * cv[nt] + bias_g[3][r];       \
        float ncc = sigm(gf) * cc[nt][r] + sigm(gi) * tanh_(gg);              \
        cc[nt][r] = ncc;                                                      \
        float hval = sigm(go) * tanh_(ncc);                                   \
        unsigned int hb16 = bf16_rne(hval);                                   \
        if (r == 0) lo = hb16;                                                \
        if (r == 1) lo |= hb16 << 16;                                         \
        if (r == 2) hi = hb16;                                                \
        if (r == 3) { hi |= hb16 << 16; hv3 = hval; }                         \
      }                                                                       \
      unsigned long long pack = (unsigned long long)lo | ((unsigned long long)hi << 32); \
      QSTOREX(nxtB + (nt ? soff1 : soff0), pack, SC);                         \
      if (jt == 31 && q == 3)                                                 \
        ys[t * (NBR * BATCH) + n * BATCH + (nt ? bb1 : bb0)] = hv3;           \
    }                                                                         \
    if (t == TLEN - 1) break;                                                 \
    WAITV(0);                                                                 \
    const unsigned tgt = (unsigned)(t + 1);                                   \
    if (FM) {                                                                 \
      if (lane == 0) { DSTOREX(myflag, tgt, "sc0");                           \
                       DSTOREX(myflag, tgt, "sc0 sc1"); }                     \
      int spins = 0;                                                          \
      for (;;) {                                                              \
        unsigned f0v, f1v;                                                    \
        INVL1();                      /* drop stale L1 copy of the flag line */ \
        if (spins < 128) { DLOADX(f0v, pf0, "sc0"); DLOADX(f1v, pf1, "sc0"); } \
        else { DLOADX(f0v, pf0, "sc0 sc1"); DLOADX(f1v, pf1, "sc0 sc1"); }    \
        WAITV(0);                                                             \
        if (__all((int)(f0v >= tgt && f1v >= tgt))) break;                    \
        ++spins; __builtin_amdgcn_s_sleep(1);                                 \
      }                                                                       \
      INVL1();                        /* h lines fresh for next step's loads */ \
    } else {                                                                  \
      if (lane == 0) DSTOREX(myflag, tgt, "sc0 sc1");                         \
      for (;;) {                                                              \
        unsigned f0v, f1v;                                                    \
        DLOADX(f0v, pf0, "sc0 sc1");                                          \
        DLOADX(f1v, pf1, "sc0 sc1");                                          \
        WAITV(0);                                                             \
        if (__all((int)(f0v >= tgt && f1v >= tgt))) break;                    \
        __builtin_amdgcn_s_sleep(1);                                          \
      }                                                                       \
    }                                                                         \
    char* tsw = curB; curB = nxtB; nxtB = tsw;                                \
  }

__global__ __launch_bounds__(256, 1) void lstm_main(
    const float* __restrict__ c_in,   // (128,256)
    const float* __restrict__ Wih,    // (8,2048)
    const float* __restrict__ Whh,    // (8,2048,512)
    const float* __restrict__ b_ih,   // (8,2048)
    const float* __restrict__ b_hh,   // (8,2048)
    char* __restrict__ hImp,          // 2MB: impure ping+pong, pre-zeroed
    char* __restrict__ hPure,         // 2MB: 8 XCD regions x (128KB ping + 128KB pong)
    float* __restrict__ ys,           // (256,8,128)
    unsigned int* __restrict__ iflags,// 8x128 impure flags, pre-zeroed
    unsigned int* __restrict__ pflags,// 8x128 pure flags (XCD-indexed), owner-scrubbed
    unsigned int* __restrict__ vx,    // 256 tagged XCC slots, pre-zeroed
    unsigned int* __restrict__ vdict, // 8 verdicts, pre-zeroed
    unsigned int* __restrict__ ibar)  // 8x32 init-barrier slots (XCD-indexed), pre-zeroed
{
  __shared__ uint4 Wlds[4096];  // 64KB

  const int tid  = threadIdx.x;
  const int lane = tid & 63;
  const int w    = tid >> 6;
  const int ln15 = lane & 15;
  const int q    = lane >> 4;
  const int n    = blockIdx.x & 7;    // branch
  const int jt   = blockIdx.x >> 3;   // 0..31 hidden-col tile
  const int j0   = jt << 4;
  const int swz  = ln15 & 7;

  // ---- publish tagged XCC_ID (straight-line, at entry) ----
  unsigned xcc_raw;
  asm volatile("s_getreg_b32 %0, hwreg(HW_REG_XCC_ID)" : "=s"(xcc_raw));
  const unsigned xcc = xcc_raw & 0xFu;
  if (tid == 0) DSTOREX(&vx[blockIdx.x], 0xA5000000u | xcc, "sc0 sc1");

  // ---- stage Whh slice -> LDS bf16 (once) ----
  for (int idx = tid; idx < 4096; idx += 256) {
    int row  = idx >> 6;
    int kc   = idx & 63;
    int tp   = row >> 4;
    int wcol = row & 15;
    const float* src = Whh + ((size_t)(n * 2048 + tp * 512 + j0 + wcol) * 512 + kc * 8);
    float4 f0 = *(const float4*)(src);
    float4 f1 = *(const float4*)(src + 4);
    uint4 v;
    v.x = (unsigned)bf16_rne(f0.x) | ((unsigned)bf16_rne(f0.y) << 16);
    v.y = (unsigned)bf16_rne(f0.z) | ((unsigned)bf16_rne(f0.w) << 16);
    v.z = (unsigned)bf16_rne(f1.x) | ((unsigned)bf16_rne(f1.y) << 16);
    v.w = (unsigned)bf16_rne(f1.z) | ((unsigned)bf16_rne(f1.w) << 16);
    Wlds[(row << 6) | (kc ^ (wcol & 7))] = v;
  }

  float wih_g[4][4], bias_g[4][4];
#pragma unroll
  for (int tp = 0; tp < 4; ++tp)
#pragma unroll
    for (int r = 0; r < 4; ++r) {
      int g = n * 2048 + tp * 512 + j0 + 4 * q + r;
      wih_g[tp][r]  = Wih[g];
      bias_g[tp][r] = b_ih[g] + b_hh[g];
    }

  // ---- leader (jt==0, wave 0): bounded purity check, publish verdict ----
  if (jt == 0 && w == 0) {
    const unsigned ref = 0xA5000000u | xcc;
    unsigned v0 = 0, v1 = 0, v2 = 0, v3 = 0;
    int ok = 0;
    for (int it = 0; it < 16384; ++it) {
      DLOADX(v0, &vx[lane],       "sc0 sc1");
      DLOADX(v1, &vx[lane + 64],  "sc0 sc1");
      DLOADX(v2, &vx[lane + 128], "sc0 sc1");
      DLOADX(v3, &vx[lane + 192], "sc0 sc1");
      WAITV(0);
      if (__all((int)(((v0 & 0xFF000000u) == 0xA5000000u) &&
                      ((v1 & 0xFF000000u) == 0xA5000000u) &&
                      ((v2 & 0xFF000000u) == 0xA5000000u) &&
                      ((v3 & 0xFF000000u) == 0xA5000000u)))) { ok = 1; break; }
      __builtin_amdgcn_s_sleep(1);
    }
    unsigned verdict = 0;
    if (ok) {
      const bool mine = ((lane & 7) == n);   // slots with idx%8==n are my branch
      int uni = __all((int)(!mine || (v0 == ref && v1 == ref && v2 == ref && v3 == ref)));
      int oth = __all((int)( mine || (v0 != ref && v1 != ref && v2 != ref && v3 != ref)));
      verdict = (uni && oth && (xcc < 8u)) ? 1u : 0u;
    }
    if (lane == 0)
      DSTOREX(&vdict[n], 0xB5000000u | (verdict << 8) | xcc, "sc0 sc1");
  }

  // ---- all blocks: wait for own leader's verdict ----
  unsigned vd;
  for (;;) {
    DLOADX(vd, &vdict[n], "sc0 sc1");
    WAITV(0);
    if ((vd & 0xFF000000u) == 0xB5000000u) break;
    __builtin_amdgcn_s_sleep(2);
  }
  const int pure   = (int)((vd >> 8) & 1u);
  const unsigned x = vd & 0xFu;       // leader's XCD (== mine if pure)

  const int bb0 = w * 32 + ln15;
  const int bb1 = bb0 + 16;
  const size_t hoff0 = ((size_t)bb0 * 64 + q) * 16;   // batch-local byte offsets
  const size_t hoff1 = ((size_t)bb1 * 64 + q) * 16;
  const size_t soff0 = ((size_t)bb0 * 128 + jt * 4 + q) * 8;
  const size_t soff1 = ((size_t)bb1 * 128 + jt * 4 + q) * 8;

  const int wrow[4] = { (0 * 16 + ln15) << 6, (1 * 16 + ln15) << 6,
                        (2 * 16 + ln15) << 6, (3 * 16 + ln15) << 6 };

  float cc[2][4];
#pragma unroll
  for (int a = 0; a < 2; ++a)
#pragma unroll
    for (int r = 0; r < 4; ++r) cc[a][r] = 0.0f;

  char *curB, *nxtB;
  unsigned int *flagB;
  if (pure) { curB = hPure + (size_t)x * 262144; nxtB = curB + 131072; flagB = pflags + x * 128; }
  else      { curB = hImp  + (size_t)n * 131072; nxtB = curB + (size_t)NBR * 131072; flagB = iflags + n * 128; }
  unsigned int* myflag = flagB + jt * 4 + w;
  const unsigned int* pf0 = flagB + lane;
  const unsigned int* pf1 = flagB + 64 + lane;

  __syncthreads();   // Wlds ready; every wave has the verdict

  if (pure) {
    // scrub my 1/32 of region[x] (8KB) to 0 == initial h state (stale dirty
    // lines for region[x] can only live in THIS XCD's L2 -> overwritten here)
    char* rp = hPure + (size_t)x * 262144 + (size_t)jt * 8192;
    for (int i = tid; i < 1024; i += 256)
      QSTOREXO(rp + (size_t)i * 8, 0ull, "0", "sc0");
    // owner-scrub my 4 flag slots (double-store: L2 + MALL truth)
    if (tid < 4) {
      DSTOREX(&flagB[jt * 4 + tid], 0u, "sc0");
      DSTOREX(&flagB[jt * 4 + tid], 0u, "sc0 sc1");
    }
    WAITV(0);
    __syncthreads();
    // branch-local init barrier at MALL scope
    if (tid == 0) DSTOREX(&ibar[x * 32 + jt], 1u, "sc0 sc1");
    for (;;) {
      unsigned iv;
      DLOADX(iv, &ibar[x * 32 + (lane & 31)], "sc0 sc1");
      WAITV(0);
      if (__all((int)(iv >= 1u))) break;
      __builtin_amdgcn_s_sleep(2);
    }
    INVL1();   // L1 may hold pre-scrub lines from a previous replay
    STEP_LOOP("sc0", 1)
  } else {
    STEP_LOOP("sc0 sc1", 0)
  }
}

// out[b,j] = sum_t (sum_n ys[t,n,b] * x[n,b,t]) * Wl[j,t] + bl[j]
__global__ __launch_bounds__(256) void finalize_k(
    const float* __restrict__ ys, const float* __restrict__ x,
    const float* __restrict__ Wl, const float* __restrict__ bl,
    float* __restrict__ out)
{
  int b = blockIdx.x;
  int tid = threadIdx.x;  // = t
  __shared__ float r[256];
  float acc = 0.f;
#pragma unroll
  for (int n = 0; n < NBR; ++n)
    acc += ys[tid * (NBR * BATCH) + n * BATCH + b] * x[(n * BATCH + b) * 256 + tid];
  r[tid] = acc;
  __syncthreads();
  int wv = tid >> 6, ln = tid & 63;
#pragma unroll
  for (int jj = 0; jj < 2; ++jj) {
    int j = wv * 2 + jj;
    float p = 0.f;
#pragma unroll
    for (int t2 = ln; t2 < 256; t2 += 64) p += r[t2] * Wl[j * 256 + t2];
#pragma unroll
    for (int s = 32; s > 0; s >>= 1) p += __shfl_down(p, s, 64);
    if (ln == 0) out[b * NBR + j] = p + bl[j];
  }
}

extern "C" void kernel_launch(void* const* d_in, const int* in_sizes, int n_in,
                              void* d_out, int out_size, void* d_ws, size_t ws_size,
                              hipStream_t stream) {
  const float* x    = (const float*)d_in[0];
  const float* c    = (const float*)d_in[1];
  const float* Wih  = (const float*)d_in[2];
  const float* Whh  = (const float*)d_in[3];
  const float* b_ih = (const float*)d_in[4];
  const float* b_hh = (const float*)d_in[5];
  // d_in[6] = hn0 (zeros; impure ping memset, pure regions scrubbed in-kernel)
  const float* Wl   = (const float*)d_in[7];
  const float* bl   = (const float*)d_in[8];
  float* out = (float*)d_out;

  char* ws = (char*)d_ws;
  char*  hImp  = ws;                                   // 2MB (ping 1MB + pong 1MB)
  char*  hPure = ws + (2u << 20);                      // 2MB (8 x 256KB, XCD-indexed)
  float* ys    = (float*)(ws + (4u << 20));            // 1MB
  unsigned int* ctrl   = (unsigned int*)(ws + (5u << 20));
  unsigned int* iflags = ctrl;                         // 1024 u32
  unsigned int* pflags = ctrl + 1024;                  // 1024 u32
  unsigned int* vx     = ctrl + 2048;                  // 256 u32
  unsigned int* vdict  = ctrl + 2304;                  // 8 u32
  unsigned int* ibar   = ctrl + 2312;                  // 256 u32

  // ws re-poisoned (0xAA) before every timed launch: re-init every call.
  (void)hipMemsetAsync(hImp, 0, 1u << 20, stream);     // impure h(t=0) = 0
  (void)hipMemsetAsync(ctrl, 0, 2568u * sizeof(unsigned int), stream);

  lstm_main<<<256, 256, 0, stream>>>(c, Wih, Whh, b_ih, b_hh, hImp, hPure, ys,
                                     iflags, pflags, vx, vdict, ibar);
  finalize_k<<<BATCH, 256, 0, stream>>>(ys, x, Wl, bl, out);
}

// Round 9
// 2039.262 us; speedup vs baseline: 111.9101x; 3.1329x over previous
//
#include <hip/hip_runtime.h>
#include <hip/hip_bf16.h>

// 8 independent LSTMs (HID=512, input=1 scalar/step) x T=256, batch 128, then a
// tiny (B,T)->(B,8) projection.
//
// Round 9: atomic-based XCD-local barrier.
//  r8 post-mortem: pure L2-local path engaged (WRITE 19MB) but EVERY step still
//  exhausted the sc0 spin budget and detected only via the MALL escalation:
//  sc0 loads (even preceded by buffer_inv sc0) do not observably return L2
//  truth for a hot polled line. Fix: flags are written AND read with
//  global_atomic_umax, which executes at the L2 (cannot be served by L1).
//   - publish: atomic_umax(tgt) at L2 + sc1 escrow at MALL (keeps escalation
//     sound); read: atomic_umax(0) sc0 = return-old at L2.
//   - one poller wave per block; 64B-padded per-block slots (no line
//     contention); waves 1-3 gate on a monotone LDS sentinel.
//   - producer order: h sc0 stores -> vmcnt(0) -> __syncthreads -> publish.
//   - one INVL1 + vmcnt(0) per step before h loads (h freshness also protected
//     by reuse distance: 256KB/step streams through the 32KB L1).
//  Impure fallback = exact r3 MALL protocol (3.88ms, proven).

#define NBR   8
#define BATCH 128
#define HIDN  512
#define TLEN  256

typedef __attribute__((ext_vector_type(8))) short bf16x8;
typedef __attribute__((ext_vector_type(4))) float f32x4;

__device__ __forceinline__ unsigned short bf16_rne(float f) {
  unsigned int u = __float_as_uint(f);
  u += 0x7FFFu + ((u >> 16) & 1u);
  return (unsigned short)(u >> 16);
}

__device__ __forceinline__ float sigm(float x) {
  return __builtin_amdgcn_rcpf(1.0f + __expf(-x));
}
__device__ __forceinline__ float tanh_(float x) {
  float ax = fabsf(x);
  float e  = __expf(-2.0f * ax);
  float t  = (1.0f - e) * __builtin_amdgcn_rcpf(1.0f + e);
  return copysignf(t, x);
}

#define HLOADX(d, p, OFF, SC) \
  asm volatile("global_load_dwordx4 %0, %1, off offset:" OFF " " SC \
               : "=v"(d) : "v"(p))
#define DLOADX(d, p, SC) \
  asm volatile("global_load_dword %0, %1, off " SC : "=v"(d) : "v"(p))
#define QSTOREX(p, v, SC) \
  asm volatile("global_store_dwordx2 %0, %1, off " SC \
               :: "v"(p), "v"(v) : "memory")
#define QSTOREXO(p, v, OFF, SC) \
  asm volatile("global_store_dwordx2 %0, %1, off offset:" OFF " " SC \
               :: "v"(p), "v"(v) : "memory")
#define DSTOREX(p, v, SC) \
  asm volatile("global_store_dword %0, %1, off " SC \
               :: "v"(p), "v"(v) : "memory")
#define WAITV(N) asm volatile("s_waitcnt vmcnt(" #N ")" ::: "memory")
#define INVL1() asm volatile("buffer_inv sc0" ::: "memory")
// L2-executed atomics: cannot be served stale by L1.
#define AUMAX_NR(p, v, SC) \
  asm volatile("global_atomic_umax %0, %1, off " SC :: "v"(p), "v"(v) : "memory")
#define AUMAX_RET(d, p, v, SC) \
  asm volatile("global_atomic_umax %0, %1, %2, off " SC \
               : "=v"(d) : "v"(p), "v"(v) : "memory")

#define CHUNK_LOAD(BUF, P0, P1, SC) do {      \
    HLOADX((BUF)[0], (P0), "0",   SC);        \
    HLOADX((BUF)[1], (P1), "0",   SC);        \
    HLOADX((BUF)[2], (P0), "64",  SC);        \
    HLOADX((BUF)[3], (P1), "64",  SC);        \
    HLOADX((BUF)[4], (P0), "128", SC);        \
    HLOADX((BUF)[5], (P1), "128", SC);        \
    HLOADX((BUF)[6], (P0), "192", SC);        \
    HLOADX((BUF)[7], (P1), "192", SC);        \
  } while (0)

#define MFMA_CHUNK(C) do {                                                    \
    _Pragma("unroll")                                                         \
    for (int k4 = 0; k4 < 4; ++k4) {                                          \
      const int ks = 4 * (C) + k4;                                            \
      bf16x8 wf[4];                                                           \
      _Pragma("unroll")                                                       \
      for (int tp = 0; tp < 4; ++tp)                                          \
        wf[tp] = __builtin_bit_cast(bf16x8, Wlds[wrow[tp] + ((4 * ks + q) ^ swz)]); \
      _Pragma("unroll")                                                       \
      for (int tp = 0; tp < 4; ++tp) {                                        \
        acc[tp][0] = __builtin_amdgcn_mfma_f32_16x16x32_bf16(                 \
            wf[tp], __builtin_bit_cast(bf16x8, hvv[C][2 * k4 + 0]), acc[tp][0], 0, 0, 0); \
        acc[tp][1] = __builtin_amdgcn_mfma_f32_16x16x32_bf16(                 \
            wf[tp], __builtin_bit_cast(bf16x8, hvv[C][2 * k4 + 1]), acc[tp][1], 0, 0, 0); \
      }                                                                       \
    }                                                                         \
  } while (0)

// FM==1: pure (sc0 h-exchange, atomic flags, LDS sentinel). FM==0: r3 MALL.
#define STEP_LOOP(SC, FM)                                                     \
  for (int t = 0; t < TLEN; ++t) {                                            \
    f32x4 acc[4][2];                                                          \
    _Pragma("unroll")                                                         \
    for (int tp = 0; tp < 4; ++tp)                                            \
      { acc[tp][0] = (f32x4){0.f,0.f,0.f,0.f}; acc[tp][1] = (f32x4){0.f,0.f,0.f,0.f}; } \
    const char* pc0 = curB + hoff0;                                           \
    const char* pc1 = curB + hoff1;                                           \
    uint4 hvv[4][8];                                                          \
    CHUNK_LOAD(hvv[0], pc0,       pc1,       SC);                             \
    CHUNK_LOAD(hvv[1], pc0 + 256, pc1 + 256, SC);                             \
    CHUNK_LOAD(hvv[2], pc0 + 512, pc1 + 512, SC);                             \
    CHUNK_LOAD(hvv[3], pc0 + 768, pc1 + 768, SC);                             \
    WAITV(24); MFMA_CHUNK(0);                                                 \
    WAITV(16); MFMA_CHUNK(1);                                                 \
    WAITV(8);  MFMA_CHUNK(2);                                                 \
    WAITV(0);  MFMA_CHUNK(3);                                                 \
    const float cv[2] = { c_in[bb0 * 256 + t], c_in[bb1 * 256 + t] };         \
    _Pragma("unroll")                                                         \
    for (int nt = 0; nt < 2; ++nt) {                                          \
      unsigned int lo = 0, hi = 0;                                            \
      float hv3 = 0.f;                                                        \
      _Pragma("unroll")                                                       \
      for (int r = 0; r < 4; ++r) {                                           \
        float gi = acc[0][nt][r] + wih_g[0][r] * cv[nt] + bias_g[0][r];       \
        float gf = acc[1][nt][r] + wih_g[1][r] * cv[nt] + bias_g[1][r];       \
        float gg = acc[2][nt][r] + wih_g[2][r] * cv[nt] + bias_g[2][r];       \
        float go = acc[3][nt][r] + wih_g[3][r] * cv[nt] + bias_g[3][r];       \
        float ncc = sigm(gf) * cc[nt][r] + sigm(gi) * tanh_(gg);              \
        cc[nt][r] = ncc;                                                      \
        float hval = sigm(go) * tanh_(ncc);                                   \
        unsigned int hb16 = bf16_rne(hval);                                   \
        if (r == 0) lo = hb16;                                                \
        if (r == 1) lo |= hb16 << 16;                                         \
        if (r == 2) hi = hb16;                                                \
        if (r == 3) { hi |= hb16 << 16; hv3 = hval; }                         \
      }                                                                       \
      unsigned long long pack = (unsigned long long)lo | ((unsigned long long)hi << 32); \
      QSTOREX(nxtB + (nt ? soff1 : soff0), pack, SC);                         \
      if (jt == 31 && q == 3)                                                 \
        ys[t * (NBR * BATCH) + n * BATCH + (nt ? bb1 : bb0)] = hv3;           \
    }                                                                         \
    if (t == TLEN - 1) break;                                                 \
    WAITV(0);                                                                 \
    const unsigned tgt = (unsigned)(t + 1);                                   \
    if (FM) {                                                                 \
      __syncthreads();             /* all 4 waves' h stores vmcnt-acked */    \
      if (w == 0) {                                                           \
        if (lane == 0) { AUMAX_NR(myflag, tgt, "");                           \
                         AUMAX_NR(myflag, tgt, "sc1"); }                      \
        const unsigned int* paddr = flagB + (lane & 31) * 16;                 \
        int spins = 0;                                                        \
        for (;;) {                                                            \
          unsigned fv = 0xFFFFFFFFu;                                          \
          if (lane < 32) {                                                    \
            if (spins < 256) { AUMAX_RET(fv, paddr, 0u, "sc0"); }             \
            else             { AUMAX_RET(fv, paddr, 0u, "sc0 sc1"); }         \
          }                                                                   \
          WAITV(0);                                                           \
          if (__all((int)(fv >= tgt))) break;                                 \
          ++spins; __builtin_amdgcn_s_sleep(1);                               \
        }                                                                     \
        if (lane == 0) sflag = tgt;                                           \
      } else {                                                                \
        while (*((volatile unsigned*)&sflag) < tgt)                           \
          __builtin_amdgcn_s_sleep(1);                                        \
      }                                                                       \
      INVL1(); WAITV(0);           /* L1 clean BEFORE next step's h loads */  \
    } else {                                                                  \
      if (lane == 0) DSTOREX(myflag, tgt, "sc0 sc1");                         \
      for (;;) {                                                              \
        unsigned f0v, f1v;                                                    \
        DLOADX(f0v, pf0, "sc0 sc1");                                          \
        DLOADX(f1v, pf1, "sc0 sc1");                                          \
        WAITV(0);                                                             \
        if (__all((int)(f0v >= tgt && f1v >= tgt))) break;                    \
        __builtin_amdgcn_s_sleep(1);                                          \
      }                                                                       \
    }                                                                         \
    char* tsw = curB; curB = nxtB; nxtB = tsw;                                \
  }

__global__ __launch_bounds__(256, 1) void lstm_main(
    const float* __restrict__ c_in,   // (128,256)
    const float* __restrict__ Wih,    // (8,2048)
    const float* __restrict__ Whh,    // (8,2048,512)
    const float* __restrict__ b_ih,   // (8,2048)
    const float* __restrict__ b_hh,   // (8,2048)
    char* __restrict__ hImp,          // 2MB impure ping+pong, pre-zeroed
    char* __restrict__ hPure,         // 2MB: 8 XCD regions x (128KB ping + 128KB pong)
    float* __restrict__ ys,           // (256,8,128)
    unsigned int* __restrict__ iflags,// 8x128 impure per-wave flags, pre-zeroed
    unsigned int* __restrict__ pflags,// 8 XCD x 32 blocks x 16 u32 (64B-padded slots)
    unsigned int* __restrict__ vx,    // 256 tagged XCC slots, pre-zeroed
    unsigned int* __restrict__ vdict, // 8 verdicts, pre-zeroed
    unsigned int* __restrict__ ibar)  // 8x32 init-barrier slots, pre-zeroed
{
  __shared__ uint4 Wlds[4096];  // 64KB
  __shared__ unsigned sflag;    // monotone intra-block release sentinel

  const int tid  = threadIdx.x;
  const int lane = tid & 63;
  const int w    = tid >> 6;
  const int ln15 = lane & 15;
  const int q    = lane >> 4;
  const int n    = blockIdx.x & 7;    // branch
  const int jt   = blockIdx.x >> 3;   // 0..31 hidden-col tile
  const int j0   = jt << 4;
  const int swz  = ln15 & 7;

  unsigned xcc_raw;
  asm volatile("s_getreg_b32 %0, hwreg(HW_REG_XCC_ID)" : "=s"(xcc_raw));
  const unsigned xcc = xcc_raw & 0xFu;
  if (tid == 0) { sflag = 0; DSTOREX(&vx[blockIdx.x], 0xA5000000u | xcc, "sc0 sc1"); }

  // ---- stage Whh slice -> LDS bf16 (once) ----
  for (int idx = tid; idx < 4096; idx += 256) {
    int row  = idx >> 6;
    int kc   = idx & 63;
    int tp   = row >> 4;
    int wcol = row & 15;
    const float* src = Whh + ((size_t)(n * 2048 + tp * 512 + j0 + wcol) * 512 + kc * 8);
    float4 f0 = *(const float4*)(src);
    float4 f1 = *(const float4*)(src + 4);
    uint4 v;
    v.x = (unsigned)bf16_rne(f0.x) | ((unsigned)bf16_rne(f0.y) << 16);
    v.y = (unsigned)bf16_rne(f0.z) | ((unsigned)bf16_rne(f0.w) << 16);
    v.z = (unsigned)bf16_rne(f1.x) | ((unsigned)bf16_rne(f1.y) << 16);
    v.w = (unsigned)bf16_rne(f1.z) | ((unsigned)bf16_rne(f1.w) << 16);
    Wlds[(row << 6) | (kc ^ (wcol & 7))] = v;
  }

  float wih_g[4][4], bias_g[4][4];
#pragma unroll
  for (int tp = 0; tp < 4; ++tp)
#pragma unroll
    for (int r = 0; r < 4; ++r) {
      int g = n * 2048 + tp * 512 + j0 + 4 * q + r;
      wih_g[tp][r]  = Wih[g];
      bias_g[tp][r] = b_ih[g] + b_hh[g];
    }

  // ---- leader (jt==0, wave 0): bounded purity check, publish verdict ----
  if (jt == 0 && w == 0) {
    const unsigned ref = 0xA5000000u | xcc;
    unsigned v0 = 0, v1 = 0, v2 = 0, v3 = 0;
    int ok = 0;
    for (int it = 0; it < 16384; ++it) {
      DLOADX(v0, &vx[lane],       "sc0 sc1");
      DLOADX(v1, &vx[lane + 64],  "sc0 sc1");
      DLOADX(v2, &vx[lane + 128], "sc0 sc1");
      DLOADX(v3, &vx[lane + 192], "sc0 sc1");
      WAITV(0);
      if (__all((int)(((v0 & 0xFF000000u) == 0xA5000000u) &&
                      ((v1 & 0xFF000000u) == 0xA5000000u) &&
                      ((v2 & 0xFF000000u) == 0xA5000000u) &&
                      ((v3 & 0xFF000000u) == 0xA5000000u)))) { ok = 1; break; }
      __builtin_amdgcn_s_sleep(1);
    }
    unsigned verdict = 0;
    if (ok) {
      const bool mine = ((lane & 7) == n);
      int uni = __all((int)(!mine || (v0 == ref && v1 == ref && v2 == ref && v3 == ref)));
      int oth = __all((int)( mine || (v0 != ref && v1 != ref && v2 != ref && v3 != ref)));
      verdict = (uni && oth && (xcc < 8u)) ? 1u : 0u;
    }
    if (lane == 0)
      DSTOREX(&vdict[n], 0xB5000000u | (verdict << 8) | xcc, "sc0 sc1");
  }

  unsigned vd;
  for (;;) {
    DLOADX(vd, &vdict[n], "sc0 sc1");
    WAITV(0);
    if ((vd & 0xFF000000u) == 0xB5000000u) break;
    __builtin_amdgcn_s_sleep(2);
  }
  const int pure   = (int)((vd >> 8) & 1u);
  const unsigned x = vd & 0xFu;

  const int bb0 = w * 32 + ln15;
  const int bb1 = bb0 + 16;
  const size_t hoff0 = ((size_t)bb0 * 64 + q) * 16;
  const size_t hoff1 = ((size_t)bb1 * 64 + q) * 16;
  const size_t soff0 = ((size_t)bb0 * 128 + jt * 4 + q) * 8;
  const size_t soff1 = ((size_t)bb1 * 128 + jt * 4 + q) * 8;

  const int wrow[4] = { (0 * 16 + ln15) << 6, (1 * 16 + ln15) << 6,
                        (2 * 16 + ln15) << 6, (3 * 16 + ln15) << 6 };

  float cc[2][4];
#pragma unroll
  for (int a = 0; a < 2; ++a)
#pragma unroll
    for (int r = 0; r < 4; ++r) cc[a][r] = 0.0f;

  char *curB, *nxtB;
  unsigned int *flagB, *myflag;
  const unsigned int *pf0, *pf1;
  if (pure) {
    curB = hPure + (size_t)x * 262144; nxtB = curB + 131072;
    flagB = pflags + x * 512;                 // 32 slots x 16 u32 (64B stride)
    myflag = flagB + jt * 16; pf0 = flagB; pf1 = flagB;      // pf unused
  } else {
    curB = hImp + (size_t)n * 131072; nxtB = curB + (size_t)NBR * 131072;
    flagB = iflags + n * 128;
    myflag = flagB + jt * 4 + w; pf0 = flagB + lane; pf1 = flagB + 64 + lane;
  }

  __syncthreads();   // Wlds + sflag ready; every wave has the verdict

  if (pure) {
    // scrub my 1/32 of region[x] to 0 (stale dirty lines live only in THIS L2)
    char* rp = hPure + (size_t)x * 262144 + (size_t)jt * 8192;
    for (int i = tid; i < 1024; i += 256)
      QSTOREXO(rp + (size_t)i * 8, 0ull, "0", "sc0");
    // scrub my flag line: L2 first (dirty-0), THEN MALL (eviction-safe order)
    if (tid == 0) {
      DSTOREX(&flagB[jt * 16], 0u, "sc0");
      WAITV(0);
      DSTOREX(&flagB[jt * 16], 0u, "sc0 sc1");
    }
    WAITV(0);
    __syncthreads();
    if (tid == 0) DSTOREX(&ibar[x * 32 + jt], 1u, "sc0 sc1");
    for (;;) {
      unsigned iv;
      DLOADX(iv, &ibar[x * 32 + (lane & 31)], "sc0 sc1");
      WAITV(0);
      if (__all((int)(iv >= 1u))) break;
      __builtin_amdgcn_s_sleep(2);
    }
    INVL1(); WAITV(0);
    STEP_LOOP("sc0", 1)
  } else {
    STEP_LOOP("sc0 sc1", 0)
  }
}

// out[b,j] = sum_t (sum_n ys[t,n,b] * x[n,b,t]) * Wl[j,t] + bl[j]
__global__ __launch_bounds__(256) void finalize_k(
    const float* __restrict__ ys, const float* __restrict__ x,
    const float* __restrict__ Wl, const float* __restrict__ bl,
    float* __restrict__ out)
{
  int b = blockIdx.x;
  int tid = threadIdx.x;  // = t
  __shared__ float r[256];
  float acc = 0.f;
#pragma unroll
  for (int n = 0; n < NBR; ++n)
    acc += ys[tid * (NBR * BATCH) + n * BATCH + b] * x[(n * BATCH + b) * 256 + tid];
  r[tid] = acc;
  __syncthreads();
  int wv = tid >> 6, ln = tid & 63;
#pragma unroll
  for (int jj = 0; jj < 2; ++jj) {
    int j = wv * 2 + jj;
    float p = 0.f;
#pragma unroll
    for (int t2 = ln; t2 < 256; t2 += 64) p += r[t2] * Wl[j * 256 + t2];
#pragma unroll
    for (int s = 32; s > 0; s >>= 1) p += __shfl_down(p, s, 64);
    if (ln == 0) out[b * NBR + j] = p + bl[j];
  }
}

extern "C" void kernel_launch(void* const* d_in, const int* in_sizes, int n_in,
                              void* d_out, int out_size, void* d_ws, size_t ws_size,
                              hipStream_t stream) {
  const float* x    = (const float*)d_in[0];
  const float* c    = (const float*)d_in[1];
  const float* Wih  = (const float*)d_in[2];
  const float* Whh  = (const float*)d_in[3];
  const float* b_ih = (const float*)d_in[4];
  const float* b_hh = (const float*)d_in[5];
  // d_in[6] = hn0 (zeros; impure ping memset, pure regions scrubbed in-kernel)
  const float* Wl   = (const float*)d_in[7];
  const float* bl   = (const float*)d_in[8];
  float* out = (float*)d_out;

  char* ws = (char*)d_ws;
  char*  hImp  = ws;                                   // 2MB
  char*  hPure = ws + (2u << 20);                      // 2MB (8 x 256KB, XCD-indexed)
  float* ys    = (float*)(ws + (4u << 20));            // 1MB
  unsigned int* ctrl   = (unsigned int*)(ws + (5u << 20));
  unsigned int* iflags = ctrl;                         // 1024 u32
  unsigned int* pflags = ctrl + 1024;                  // 4096 u32 (8x32x16)
  unsigned int* vx     = ctrl + 5120;                  // 256 u32
  unsigned int* vdict  = ctrl + 5376;                  // 8 u32
  unsigned int* ibar   = ctrl + 5384;                  // 256 u32

  // ws re-poisoned (0xAA) before every timed launch: re-init every call.
  (void)hipMemsetAsync(hImp, 0, 1u << 20, stream);     // impure h(t=0) = 0
  (void)hipMemsetAsync(ctrl, 0, 5640u * sizeof(unsigned int), stream);

  lstm_main<<<256, 256, 0, stream>>>(c, Wih, Whh, b_ih, b_hh, hImp, hPure, ys,
                                     iflags, pflags, vx, vdict, ibar);
  finalize_k<<<BATCH, 256, 0, stream>>>(ys, x, Wl, bl, out);
}